// Round 12
// baseline (367.940 us; speedup 1.0000x reference)
//
#include <hip/hip_runtime.h>
#include <math.h>

#define BB 48
#define LL 512
#define DD 192
#define HH 6
#define DKK 32
#define HID 768
#define ROWS (BB * LL)
#define BLD ((size_t)ROWS * DD)
#define SB2 0.25503531f                 // (1/sqrt(32)) * log2(e)
#define MASKED_X (-36.0f)               // exp2(-36) ~= 1.5e-11 (uniform floor)

typedef unsigned short ushort_t;
typedef unsigned int uint_t;
typedef __bf16 bf16x8 __attribute__((ext_vector_type(8)));
typedef float f32x4 __attribute__((ext_vector_type(4)));

union U4BF8 { uint4 u; bf16x8 b; };
union BFU { __bf16 h; ushort_t u; };

__device__ __forceinline__ ushort_t f2bf(float f) {
  union { float f; uint_t u; } v; v.f = f;
  uint_t r = v.u + 0x7fffu + ((v.u >> 16) & 1u);
  return (ushort_t)(r >> 16);
}
__device__ __forceinline__ ushort_t cvt_bf(float f) {
  BFU c; c.h = (__bf16)f; return c.u;
}

// Swizzled weight offset: fragment-major so a wave's dwordx4 load of one
// 16x32 (n x k) MFMA B-tile is lane-linear (fully coalesced 1KB/wave).
__device__ __forceinline__ int swz_w(int n, int k, int N) {
  return ((k >> 5) * (N >> 4) + (n >> 4)) * 512 +
         ((((k & 31) >> 3) << 4) + (n & 15)) * 8 + (k & 7);
}

// ---------------------------------------------------------------------------
__global__ __launch_bounds__(256) void pack_kernel(
    const float* __restrict__ wq, const float* __restrict__ wk,
    const float* __restrict__ wv, const float* __restrict__ wo,
    const float* __restrict__ w1, const float* __restrict__ w2,
    const float* __restrict__ bq, const float* __restrict__ bk,
    const float* __restrict__ bv,
    ushort_t* __restrict__ Wqkv, ushort_t* __restrict__ Wo,
    ushort_t* __restrict__ W1, ushort_t* __restrict__ W2,
    float* __restrict__ bqkv) {
  int i = blockIdx.x * 256 + threadIdx.x;
  if (i < 110592) {                       // Wqkv swizzled, N=576
    int n2 = i / 192, k = i - n2 * 192;
    int part = n2 / 192, n = n2 - part * 192;
    const float* src = part == 0 ? wq : (part == 1 ? wk : wv);
    Wqkv[swz_w(n2, k, 576)] = f2bf(src[k * 192 + n]);
  } else if (i < 147456) {                // Wo swizzled, N=192
    int j = i - 110592;
    int n = j / 192, k = j - n * 192;
    Wo[swz_w(n, k, 192)] = f2bf(wo[k * 192 + n]);
  } else if (i < 294912) {                // W1_t [768][192]
    int j = i - 147456;
    int n = j / 192, k = j - n * 192;
    W1[j] = f2bf(w1[k * 768 + n]);
  } else if (i < 442368) {                // W2_t [192][768]
    int j = i - 294912;
    int n = j / 768, k = j - n * 768;
    W2[j] = f2bf(w2[k * 192 + n]);
  } else if (i < 442944) {                // bqkv [576]
    int j = i - 442368;
    bqkv[j] = j < 192 ? bq[j] : (j < 384 ? bk[j - 192] : bv[j - 384]);
  }
}

// ---------------------------------------------------------------------------
// Fused pre-LN + QKV projection. Block = 32 rows x 576 cols, 256 threads.
// ---------------------------------------------------------------------------
__global__ __launch_bounds__(256) void qkv_ln_kernel(
    const float* __restrict__ xa, const float* __restrict__ xb,
    const int* __restrict__ va, const int* __restrict__ vb,
    const float* __restrict__ g_a, const float* __restrict__ b_a,
    const float* __restrict__ g_b, const float* __restrict__ b_b,
    const ushort_t* __restrict__ Wsw, const float* __restrict__ bias,
    ushort_t* __restrict__ Cb) {
  constexpr int N = 576;
  constexpr int CSB = N + 8;
  __shared__ ushort_t smem[32 * CSB];    // 37.4 KB; As (12.8 KB) overlays
  ushort_t* As = smem;

  int tid = threadIdx.x;
  int w = tid >> 6, lane = tid & 63, l15 = lane & 15, kq = lane >> 4;
  int row0 = blockIdx.x * 32;
  int side = row0 >= ROWS;
  int rb = row0 - side * ROWS;

  // --- phase 1: masked LN, x fp32 -> As bf16 ---
  {
    int row = tid >> 3, l8 = tid & 7;
    const float* xr = (side ? xb : xa) + (size_t)(rb + row) * DD + l8 * 24;
    float v[24];
    float s = 0.f;
#pragma unroll
    for (int j = 0; j < 6; ++j) {
      float4 q = *(const float4*)(xr + j * 4);
      v[j*4+0] = q.x; v[j*4+1] = q.y; v[j*4+2] = q.z; v[j*4+3] = q.w;
      s += q.x + q.y + q.z + q.w;
    }
    s += __shfl_xor(s, 1); s += __shfl_xor(s, 2); s += __shfl_xor(s, 4);
    float mu = s * (1.0f / 192.0f);
    float ss = 0.f;
#pragma unroll
    for (int j = 0; j < 24; ++j) { float d = v[j] - mu; ss += d * d; }
    ss += __shfl_xor(ss, 1); ss += __shfl_xor(ss, 2); ss += __shfl_xor(ss, 4);
    float inv = rsqrtf(ss * (1.0f / 192.0f) + 1e-5f);
    int vld = (side ? vb : va)[rb + row];
    const float* g = side ? g_b : g_a;
    const float* be = side ? b_b : b_a;
    ushort_t ob[24];
#pragma unroll
    for (int j = 0; j < 24; ++j) {
      int col = l8 * 24 + j;
      float r = vld ? (v[j] - mu) * inv * g[col] + be[col] : v[j];
      ob[j] = f2bf(r);
    }
#pragma unroll
    for (int j = 0; j < 3; ++j)
      *(uint4*)(&As[row * 200 + l8 * 24 + j * 8]) = *(const uint4*)(&ob[j * 8]);
  }
  __syncthreads();

  // --- phase 2: GEMM ---
  f32x4 acc[2][9];
#pragma unroll
  for (int qs = 0; qs < 2; ++qs)
#pragma unroll
    for (int nt = 0; nt < 9; ++nt) acc[qs][nt] = (f32x4){0.f, 0.f, 0.f, 0.f};

#pragma unroll 1
  for (int kk = 0; kk < 6; ++kk) {
    bf16x8 af[2];
#pragma unroll
    for (int qs = 0; qs < 2; ++qs)
      af[qs] = *(const bf16x8*)(&As[(qs * 16 + l15) * 200 + kk * 32 + kq * 8]);
    const ushort_t* wp =
        Wsw + ((size_t)(kk * (N >> 4) + w * 9) << 9) + lane * 8;
#pragma unroll
    for (int nt = 0; nt < 9; ++nt) {
      U4BF8 wf;
      wf.u = *(const uint4*)(wp + (nt << 9));
#pragma unroll
      for (int qs = 0; qs < 2; ++qs)
        acc[qs][nt] = __builtin_amdgcn_mfma_f32_16x16x32_bf16(
            af[qs], wf.b, acc[qs][nt], 0, 0, 0);
    }
  }
  __syncthreads();  // As dead; smem reused for C staging

  // --- phase 3: bias -> LDS -> linear full-line bf16 stores ---
  ushort_t* Cs = smem;
#pragma unroll
  for (int nt = 0; nt < 9; ++nt) {
    int col = (w * 9 + nt) * 16 + l15;
    float bb = bias[col];
#pragma unroll
    for (int qs = 0; qs < 2; ++qs)
#pragma unroll
      for (int r = 0; r < 4; ++r)
        Cs[(qs * 16 + kq * 4 + r) * CSB + col] = f2bf(acc[qs][nt][r] + bb);
  }
  __syncthreads();
  constexpr int UPR = (N * 2) / 16;
#pragma unroll
  for (int i = 0; i < (32 * UPR) / 256; ++i) {
    int idx = tid + i * 256;
    int r = idx / UPR, u = idx - r * UPR;
    *(uint4*)(Cb + (size_t)row0 * N + idx * 8) =
        *(const uint4*)(&Cs[r * CSB + u * 8]);
  }
}

// ---------------------------------------------------------------------------
// Merged O-projection + residual-LN-chain + FFN + final residual-LN.
// Block = 64 rows, 256 threads. Everything after attention is row-local:
//   y = mln(attO@Wo + bo + x, ln_o)   [y kept in REGISTERS, 48/thread]
//   z = mln(y, fln)                   [written straight into As LDS]
//   out = mln(y + ffn(z), flno)
// Eliminates the y and lnFull global round-trips (~113 MB) and one launch.
// LDS aliasing (As/Hs/Cs) is fenced by barriers at each live-range boundary.
// ---------------------------------------------------------------------------
__global__ __launch_bounds__(256, 3) void oproj_ffn_kernel(
    const ushort_t* __restrict__ A, const ushort_t* __restrict__ Wosw,
    const float* __restrict__ bo,
    const float* __restrict__ xa, const float* __restrict__ xb,
    const int* __restrict__ va, const int* __restrict__ vb,
    const float* __restrict__ g_oa, const float* __restrict__ b_oa,
    const float* __restrict__ g_ob, const float* __restrict__ b_ob,
    const float* __restrict__ g_f, const float* __restrict__ b_f,
    const ushort_t* __restrict__ W1t, const float* __restrict__ bias1,
    const ushort_t* __restrict__ W2t, const float* __restrict__ bias2,
    const float* __restrict__ g_fo, const float* __restrict__ b_fo,
    float* __restrict__ outf) {
  __shared__ float smemf[64 * 196];      // 50.2 KB; overlays:
  ushort_t* As = (ushort_t*)smemf;       //   As 64*200 us (25.6 KB)
  ushort_t* Hs = As + 64 * 200;          //   Hs 2*64*72 us (18.4 KB)
  float* Cs = smemf;                     //   Cs 64*196 f32 (full)

  int tid = threadIdx.x;
  int w = tid >> 6, lane = tid & 63, l15 = lane & 15, kq = lane >> 4;
  int row0 = blockIdx.x * 64;
  int side = row0 >= ROWS;
  int rb0 = row0 - side * ROWS;

  // ---- 1. stage attO 64x192 bf16 ----
#pragma unroll
  for (int i = 0; i < 6; ++i) {
    int idx = tid + i * 256;
    int r = idx / 24, c = (idx % 24) * 8;
    *(uint4*)(&As[r * 200 + c]) = *(const uint4*)(A + (size_t)(row0 + r) * DD + c);
  }
  __syncthreads();

  // ---- 2. O-projection GEMM: wave w owns cols w*48..+47, all 64 rows ----
  f32x4 Cacc[4][3];
#pragma unroll
  for (int qs = 0; qs < 4; ++qs)
#pragma unroll
    for (int nt = 0; nt < 3; ++nt) Cacc[qs][nt] = (f32x4){0.f, 0.f, 0.f, 0.f};

#pragma unroll 1
  for (int kk = 0; kk < 6; ++kk) {
    bf16x8 af[4];
#pragma unroll
    for (int qs = 0; qs < 4; ++qs)
      af[qs] = *(const bf16x8*)(&As[(qs * 16 + l15) * 200 + kk * 32 + kq * 8]);
    const ushort_t* wp = Wosw + ((size_t)(kk * 12 + w * 3) << 9) + lane * 8;
#pragma unroll
    for (int nt = 0; nt < 3; ++nt) {
      U4BF8 wf;
      wf.u = *(const uint4*)(wp + (nt << 9));
#pragma unroll
      for (int qs = 0; qs < 4; ++qs)
        Cacc[qs][nt] = __builtin_amdgcn_mfma_f32_16x16x32_bf16(
            af[qs], wf.b, Cacc[qs][nt], 0, 0, 0);
    }
  }
  __syncthreads();   // As dead -> Cs (aliases As) may be written

  // ---- 3. stage Cs = C + bo ----
#pragma unroll
  for (int qs = 0; qs < 4; ++qs)
#pragma unroll
    for (int nt = 0; nt < 3; ++nt) {
      int col = w * 48 + nt * 16 + l15;
      float bb = bo[col];
#pragma unroll
      for (int r = 0; r < 4; ++r)
        Cs[(qs * 16 + kq * 4 + r) * 196 + col] = Cacc[qs][nt][r] + bb;
    }
  __syncthreads();

  // ---- 4. row phase 1: y = mln(C+x, ln_o); z = mln(y, fln) -> As ----
  int row = tid >> 2, l4 = tid & 3;
  int vld = (side ? vb : va)[rb0 + row];
  const float* xrow = (side ? xb : xa) + (size_t)(rb0 + row) * DD;
  const float* crow = &Cs[row * 196];
  const float* g1 = side ? g_ob : g_oa;
  const float* b1 = side ? b_ob : b_oa;
  float y[48];
  float s = 0.f;
#pragma unroll
  for (int j = 0; j < 12; ++j) {
    int col = j * 16 + l4 * 4;
    float4 q = *(const float4*)(xrow + col);
    y[j*4+0] = crow[col+0] + q.x; y[j*4+1] = crow[col+1] + q.y;
    y[j*4+2] = crow[col+2] + q.z; y[j*4+3] = crow[col+3] + q.w;
    s += y[j*4+0] + y[j*4+1] + y[j*4+2] + y[j*4+3];
  }
  s += __shfl_xor(s, 1); s += __shfl_xor(s, 2);
  float mu = s * (1.0f / 192.0f);
  float ss = 0.f;
#pragma unroll
  for (int j = 0; j < 48; ++j) { float d = y[j] - mu; ss += d * d; }
  ss += __shfl_xor(ss, 1); ss += __shfl_xor(ss, 2);
  float inv = rsqrtf(ss * (1.0f / 192.0f) + 1e-5f);
#pragma unroll
  for (int j = 0; j < 12; ++j)
#pragma unroll
    for (int e = 0; e < 4; ++e) {
      int col = j * 16 + l4 * 4 + e;
      float vv = y[j * 4 + e];
      y[j * 4 + e] = vld ? (vv - mu) * inv * g1[col] + b1[col] : vv;
    }
  // LN2 (fln) -> z bf16
  float s2 = 0.f;
#pragma unroll
  for (int j = 0; j < 48; ++j) s2 += y[j];
  s2 += __shfl_xor(s2, 1); s2 += __shfl_xor(s2, 2);
  float mu2 = s2 * (1.0f / 192.0f);
  float ss2 = 0.f;
#pragma unroll
  for (int j = 0; j < 48; ++j) { float e = y[j] - mu2; ss2 += e * e; }
  ss2 += __shfl_xor(ss2, 1); ss2 += __shfl_xor(ss2, 2);
  float inv2 = rsqrtf(ss2 * (1.0f / 192.0f) + 1e-5f);
  ushort_t z[48];
#pragma unroll
  for (int j = 0; j < 12; ++j)
#pragma unroll
    for (int e = 0; e < 4; ++e) {
      int col = j * 16 + l4 * 4 + e;
      float zz = vld ? (y[j*4+e] - mu2) * inv2 * g_f[col] + b_f[col] : y[j*4+e];
      z[j * 4 + e] = f2bf(zz);
    }
  __syncthreads();   // all Cs reads done -> As (aliases Cs) may be written
#pragma unroll
  for (int j = 0; j < 12; ++j)
    *(uint2*)(&As[row * 200 + j * 16 + l4 * 4]) = *(const uint2*)(&z[j * 4]);

  // ---- 5. FFN (R9 v2 body): As = z, wave w owns H cols w*16, C cols w*48 ----
  const ushort_t* w1p = W1t + (size_t)(w * 16 + l15) * DD + kq * 8;
  const ushort_t* w2p = W2t + (size_t)(w * 48 + l15) * HID + kq * 8;

  U4BF8 w1f[6], w1n[6], w2f[6];
#pragma unroll
  for (int kk = 0; kk < 6; ++kk)
    w1f[kk].u = *(const uint4*)(w1p + kk * 32);  // hc = 0

  f32x4 Facc[4][3];
#pragma unroll
  for (int qs = 0; qs < 4; ++qs)
#pragma unroll
    for (int nt = 0; nt < 3; ++nt) Facc[qs][nt] = (f32x4){0.f, 0.f, 0.f, 0.f};

  __syncthreads();   // As (FFN input) ready

  for (int hc = 0; hc < 12; ++hc) {
#pragma unroll
    for (int kk2 = 0; kk2 < 2; ++kk2)
#pragma unroll
      for (int nt = 0; nt < 3; ++nt)
        w2f[kk2 * 3 + nt].u =
            *(const uint4*)(w2p + (size_t)(nt * 16) * HID + hc * 64 + kk2 * 32);

    f32x4 Hacc[4];
#pragma unroll
    for (int qs = 0; qs < 4; ++qs) Hacc[qs] = (f32x4){0.f, 0.f, 0.f, 0.f};
#pragma unroll
    for (int kk = 0; kk < 6; ++kk) {
#pragma unroll
      for (int qs = 0; qs < 4; ++qs) {
        bf16x8 af = *(const bf16x8*)(&As[(qs * 16 + l15) * 200 + kk * 32 + kq * 8]);
        Hacc[qs] = __builtin_amdgcn_mfma_f32_16x16x32_bf16(
            af, w1f[kk].b, Hacc[qs], 0, 0, 0);
      }
    }

    if (hc < 11) {
#pragma unroll
      for (int kk = 0; kk < 6; ++kk)
        w1n[kk].u = *(const uint4*)(w1p + (size_t)(hc + 1) * 64 * DD + kk * 32);
    }

    {
      float bb = bias1[hc * 64 + w * 16 + l15];
      ushort_t* hb = &Hs[(hc & 1) * 4608];
#pragma unroll
      for (int qs = 0; qs < 4; ++qs)
#pragma unroll
        for (int r = 0; r < 4; ++r) {
          float x = Hacc[qs][r] + bb;
          x = 0.5f * x * (1.0f + erff(x * 0.70710678118654752f));
          hb[(qs * 16 + kq * 4 + r) * 72 + w * 16 + l15] = f2bf(x);
        }
    }
    __syncthreads();   // Hs[buf] complete; also fences reads of Hs[buf^1]

#pragma unroll
    for (int kk2 = 0; kk2 < 2; ++kk2) {
      bf16x8 hf[4];
#pragma unroll
      for (int qs = 0; qs < 4; ++qs)
        hf[qs] = *(const bf16x8*)(&Hs[(hc & 1) * 4608 +
                                      (qs * 16 + l15) * 72 + kk2 * 32 + kq * 8]);
#pragma unroll
      for (int nt = 0; nt < 3; ++nt)
#pragma unroll
        for (int qs = 0; qs < 4; ++qs)
          Facc[qs][nt] = __builtin_amdgcn_mfma_f32_16x16x32_bf16(
              hf[qs], w2f[kk2 * 3 + nt].b, Facc[qs][nt], 0, 0, 0);
    }

#pragma unroll
    for (int kk = 0; kk < 6; ++kk) w1f[kk] = w1n[kk];
  }
  __syncthreads();   // As/Hs dead -> Cs may be rewritten

  // ---- 6. epilogue: Cs = Facc + bias2; out = mln(y + Cs, flno) ----
#pragma unroll
  for (int qs = 0; qs < 4; ++qs)
#pragma unroll
    for (int nt = 0; nt < 3; ++nt) {
      int col = w * 48 + nt * 16 + l15;
      float bb = bias2[col];
#pragma unroll
      for (int r = 0; r < 4; ++r)
        Cs[(qs * 16 + kq * 4 + r) * 196 + col] = Facc[qs][nt][r] + bb;
    }
  __syncthreads();

  float* orow = outf + (size_t)(row0 + row) * DD;
  float s3 = 0.f;
#pragma unroll
  for (int j = 0; j < 12; ++j) {
    int col = j * 16 + l4 * 4;
#pragma unroll
    for (int e = 0; e < 4; ++e) {
      y[j * 4 + e] += crow[col + e];   // y + ffn output (y was in regs)
      s3 += y[j * 4 + e];
    }
  }
  s3 += __shfl_xor(s3, 1); s3 += __shfl_xor(s3, 2);
  float mu3 = s3 * (1.0f / 192.0f);
  float ss3 = 0.f;
#pragma unroll
  for (int j = 0; j < 48; ++j) { float d = y[j] - mu3; ss3 += d * d; }
  ss3 += __shfl_xor(ss3, 1); ss3 += __shfl_xor(ss3, 2);
  float inv3 = rsqrtf(ss3 * (1.0f / 192.0f) + 1e-5f);
#pragma unroll
  for (int j = 0; j < 12; ++j) {
    int col = j * 16 + l4 * 4;
    float4 q;
#pragma unroll
    for (int e = 0; e < 4; ++e) {
      float vv = y[j * 4 + e];
      ((float*)&q)[e] =
          vld ? (vv - mu3) * inv3 * g_fo[col + e] + b_fo[col + e] : vv;
    }
    *(float4*)(orow + col) = q;
  }
}

// ---------------------------------------------------------------------------
// MFMA flash attention (best-measured R3 variant + setprio, unchanged R9).
// ---------------------------------------------------------------------------
__global__ __launch_bounds__(256) void attn_mfma_kernel(
    const ushort_t* __restrict__ QKV,
    const int* __restrict__ valid_a, const int* __restrict__ valid_b,
    ushort_t* __restrict__ out) {
  int i = blockIdx.x;
  int gid = ((i >> 5) << 3) | (i & 7);
  int qt = (i >> 3) & 3;
  int side = gid >= BB * HH;
  int grem = side ? gid - BB * HH : gid;
  int h = grem % HH;
  int batch = grem / HH;
  int tid = threadIdx.x;
  int w = tid >> 6;
  int lane = tid & 63;
  int l15 = lane & 15;
  int kq = lane >> 4;

  const int* validq = side ? valid_b : valid_a;
  const int* validk = side ? valid_a : valid_b;
  size_t qrow0  = (size_t)side * ROWS + (size_t)batch * LL;
  size_t kvrow0 = (size_t)(1 - side) * ROWS + (size_t)batch * LL;

  __shared__ ushort_t VsT[2][32 * 72];
  __shared__ ushort_t Ps[4][32 * 72];

  int qbase = qt * 128 + w * 32;

  U4BF8 qfrag[2];
#pragma unroll
  for (int qs = 0; qs < 2; ++qs)
    qfrag[qs].u = *(const uint4*)(QKV + (qrow0 + qbase + qs * 16 + l15) * 576 +
                                  h * DKK + kq * 8);

  // per-(qs,r) fma coefficients: sqf = vq ? SB2 : 0, mq = vq ? 0 : -36
  float sqf[2][4], mq[2][4];
#pragma unroll
  for (int qs = 0; qs < 2; ++qs)
#pragma unroll
    for (int r = 0; r < 4; ++r) {
      int vq = validq[batch * LL + qbase + qs * 16 + kq * 4 + r];
      sqf[qs][r] = vq ? SB2 : 0.0f;
      mq[qs][r]  = vq ? 0.0f : MASKED_X;
    }

  float lsum[2][4];
  f32x4 Oacc[2][2];
#pragma unroll
  for (int qs = 0; qs < 2; ++qs) {
#pragma unroll
    for (int r = 0; r < 4; ++r) lsum[qs][r] = 0.0f;
#pragma unroll
    for (int ds = 0; ds < 2; ++ds) Oacc[qs][ds] = (f32x4){0.f, 0.f, 0.f, 0.f};
  }

  // prologue: load tile-0 V, K, valid
  uint4 vv = *(const uint4*)(QKV + (kvrow0 + lane) * 576 + 384 + h * DKK + w * 8);
  U4BF8 kf[4];
  int vki[4];
#pragma unroll
  for (int ks = 0; ks < 4; ++ks) {
    kf[ks].u = *(const uint4*)(QKV + (kvrow0 + ks * 16 + l15) * 576 +
                               192 + h * DKK + kq * 8);
    vki[ks] = validk[batch * LL + ks * 16 + l15];
  }

  for (int c = 0; c < LL; c += 64) {
    int buf = (c >> 6) & 1;
    // stage this tile's V (regs -> LDS), transposed to [d][k]
    {
      uint_t uu[4] = {vv.x, vv.y, vv.z, vv.w};
#pragma unroll
      for (int j = 0; j < 4; ++j) {
        VsT[buf][(w * 8 + 2 * j) * 72 + lane]     = (ushort_t)(uu[j] & 0xffffu);
        VsT[buf][(w * 8 + 2 * j + 1) * 72 + lane] = (ushort_t)(uu[j] >> 16);
      }
    }
    uint4 vvn;
    if (c + 64 < LL)
      vvn = *(const uint4*)(QKV + (kvrow0 + c + 64 + lane) * 576 +
                            384 + h * DKK + w * 8);
    __syncthreads();   // VsT[buf] ready (prev readers of buf are 2 tiles back)

    // S = Q K^T for this tile (K already in regs)
    f32x4 S[2][4];
    __builtin_amdgcn_s_setprio(1);
#pragma unroll
    for (int ks = 0; ks < 4; ++ks)
#pragma unroll
      for (int qs = 0; qs < 2; ++qs) {
        f32x4 z = (f32x4){0.f, 0.f, 0.f, 0.f};
        S[qs][ks] = __builtin_amdgcn_mfma_f32_16x16x32_bf16(
            qfrag[qs].b, kf[ks].b, z, 0, 0, 0);
      }
    __builtin_amdgcn_s_setprio(0);

    float mkb[4];
#pragma unroll
    for (int ks = 0; ks < 4; ++ks) mkb[ks] = vki[ks] ? 0.0f : MASKED_X;

    // prefetch next tile's K + valid (hidden under softmax+PV)
    U4BF8 kfn[4];
    int vkn[4];
    if (c + 64 < LL) {
#pragma unroll
      for (int ks = 0; ks < 4; ++ks) {
        kfn[ks].u = *(const uint4*)(QKV + (kvrow0 + c + 64 + ks * 16 + l15) * 576 +
                                    192 + h * DKK + kq * 8);
        vkn[ks] = validk[batch * LL + c + 64 + ks * 16 + l15];
      }
    }

    // softmax numerator: p = exp2(fma(S, sqf, min(mq, mkb)))
#pragma unroll
    for (int qs = 0; qs < 2; ++qs)
#pragma unroll
      for (int ks = 0; ks < 4; ++ks)
#pragma unroll
        for (int r = 0; r < 4; ++r) {
          float xs = fmaf(S[qs][ks][r], sqf[qs][r], fminf(mq[qs][r], mkb[ks]));
          float p = __builtin_amdgcn_exp2f(xs);
          lsum[qs][r] += p;
          Ps[w][(qs * 16 + kq * 4 + r) * 72 + ks * 16 + l15] = cvt_bf(p);
        }

    // PV
    __builtin_amdgcn_s_setprio(1);
#pragma unroll
    for (int kh = 0; kh < 2; ++kh) {
      bf16x8 pf[2], vf[2];
#pragma unroll
      for (int qs = 0; qs < 2; ++qs)
        pf[qs] = *(const bf16x8*)(&Ps[w][(qs * 16 + l15) * 72 + kh * 32 + kq * 8]);
#pragma unroll
      for (int ds = 0; ds < 2; ++ds)
        vf[ds] = *(const bf16x8*)(&VsT[buf][(ds * 16 + l15) * 72 + kh * 32 + kq * 8]);
#pragma unroll
      for (int qs = 0; qs < 2; ++qs)
#pragma unroll
        for (int ds = 0; ds < 2; ++ds)
          Oacc[qs][ds] = __builtin_amdgcn_mfma_f32_16x16x32_bf16(
              pf[qs], vf[ds], Oacc[qs][ds], 0, 0, 0);
    }
    __builtin_amdgcn_s_setprio(0);

    vv = vvn;
#pragma unroll
    for (int ks = 0; ks < 4; ++ks) { kf[ks] = kfn[ks]; vki[ks] = vkn[ks]; }
  }

#pragma unroll
  for (int qs = 0; qs < 2; ++qs)
#pragma unroll
    for (int r = 0; r < 4; ++r) {
      float sm = lsum[qs][r];
#pragma unroll
      for (int off = 1; off < 16; off <<= 1) sm += __shfl_xor(sm, off);
      lsum[qs][r] = sm;
    }

#pragma unroll
  for (int qs = 0; qs < 2; ++qs)
#pragma unroll
    for (int ds = 0; ds < 2; ++ds)
#pragma unroll
      for (int r = 0; r < 4; ++r) {
        int q = qbase + qs * 16 + kq * 4 + r;
        out[(qrow0 + q) * DD + h * DKK + ds * 16 + l15] =
            f2bf(Oacc[qs][ds][r] / lsum[qs][r]);
      }
}

// ---------------------------------------------------------------------------
extern "C" void kernel_launch(void* const* d_in, const int* in_sizes, int n_in,
                              void* d_out, int out_size, void* d_ws, size_t ws_size,
                              hipStream_t stream) {
  const float* x_a = (const float*)d_in[0];
  const float* x_b = (const float*)d_in[1];
  const int* valid_a = (const int*)d_in[2];
  const int* valid_b = (const int*)d_in[3];
  const float* ln_a_g = (const float*)d_in[4];
  const float* ln_a_b = (const float*)d_in[5];
  const float* ln_b_g = (const float*)d_in[6];
  const float* ln_b_b = (const float*)d_in[7];
  const float* ln_oa_g = (const float*)d_in[8];
  const float* ln_oa_b = (const float*)d_in[9];
  const float* ln_ob_g = (const float*)d_in[10];
  const float* ln_ob_b = (const float*)d_in[11];
  const float* wq = (const float*)d_in[12];
  const float* bq = (const float*)d_in[13];
  const float* wk = (const float*)d_in[14];
  const float* bk = (const float*)d_in[15];
  const float* wv = (const float*)d_in[16];
  const float* bv = (const float*)d_in[17];
  const float* wo = (const float*)d_in[18];
  const float* bo = (const float*)d_in[19];
  const float* fln_g = (const float*)d_in[20];
  const float* fln_b = (const float*)d_in[21];
  const float* flno_g = (const float*)d_in[22];
  const float* flno_b = (const float*)d_in[23];
  const float* w1 = (const float*)d_in[24];
  const float* b1 = (const float*)d_in[25];
  const float* w2 = (const float*)d_in[26];
  const float* b2 = (const float*)d_in[27];

  // Workspace: weights [0, 887040); attO bf16 [2R,192] at 887040;
  // QKV bf16 [2R,576] at 19761408.
  char* wsb = (char*)d_ws;
  ushort_t* Wqkv = (ushort_t*)wsb;
  ushort_t* Wo_t = Wqkv + 110592;
  ushort_t* W1_t = Wo_t + 36864;
  ushort_t* W2_t = W1_t + 147456;
  float*    bqkv = (float*)(W2_t + 147456);
  ushort_t* attO = (ushort_t*)(wsb + 887040);
  ushort_t* QKV = (ushort_t*)(wsb + 19761408);

  float* out_a = (float*)d_out;   // [2R,192] fp32 contiguous

  dim3 b256(256);
  dim3 gGemm(2 * ROWS / 32);                    // 1536 row-blocks
  dim3 gAttn(BB * HH * 4 * 2);                  // 2304
  dim3 gOF(2 * ROWS / 64);                      // 768 (64-row merged blocks)

  hipLaunchKernelGGL(pack_kernel, dim3(1731), b256, 0, stream,
                     wq, wk, wv, wo, w1, w2, bq, bk, bv,
                     Wqkv, Wo_t, W1_t, W2_t, bqkv);

  // 1+2. fused pre-LN + QKV projection, both sides
  hipLaunchKernelGGL(qkv_ln_kernel, gGemm, b256, 0, stream,
                     x_a, x_b, valid_a, valid_b,
                     ln_a_g, ln_a_b, ln_b_g, ln_b_b,
                     Wqkv, bqkv, QKV);

  // 3. attention, both sides
  hipLaunchKernelGGL(attn_mfma_kernel, gAttn, b256, 0, stream,
                     QKV, valid_a, valid_b, attO);

  // 4-8. merged O-proj + residual-LN chain + FFN + final residual-LN
  hipLaunchKernelGGL(oproj_ffn_kernel, gOF, b256, 0, stream,
                     attO, Wo_t, bo, x_a, x_b, valid_a, valid_b,
                     ln_oa_g, ln_oa_b, ln_ob_g, ln_ob_b, fln_g, fln_b,
                     W1_t, b1, W2_t, b2, flno_g, flno_b,
                     out_a);
}

// Round 13
// 358.700 us; speedup vs baseline: 1.0258x; 1.0258x over previous
//
#include <hip/hip_runtime.h>
#include <math.h>

#define BB 48
#define LL 512
#define DD 192
#define HH 6
#define DKK 32
#define HID 768
#define ROWS (BB * LL)
#define BLD ((size_t)ROWS * DD)
#define SB2 0.25503531f                 // (1/sqrt(32)) * log2(e)
#define MASKED_X (-36.0f)               // exp2(-36) ~= 1.5e-11 (uniform floor)

typedef unsigned short ushort_t;
typedef unsigned int uint_t;
typedef __bf16 bf16x8 __attribute__((ext_vector_type(8)));
typedef float f32x4 __attribute__((ext_vector_type(4)));

union U4BF8 { uint4 u; bf16x8 b; };
union BFU { __bf16 h; ushort_t u; };

__device__ __forceinline__ ushort_t f2bf(float f) {
  union { float f; uint_t u; } v; v.f = f;
  uint_t r = v.u + 0x7fffu + ((v.u >> 16) & 1u);
  return (ushort_t)(r >> 16);
}
__device__ __forceinline__ ushort_t cvt_bf(float f) {
  BFU c; c.h = (__bf16)f; return c.u;
}

// Swizzled weight offset: fragment-major so a wave's dwordx4 load of one
// 16x32 (n x k) MFMA B-tile is lane-linear (fully coalesced 1KB/wave).
__device__ __forceinline__ int swz_w(int n, int k, int N) {
  return ((k >> 5) * (N >> 4) + (n >> 4)) * 512 +
         ((((k & 31) >> 3) << 4) + (n & 15)) * 8 + (k & 7);
}

// ---------------------------------------------------------------------------
__global__ __launch_bounds__(256) void pack_kernel(
    const float* __restrict__ wq, const float* __restrict__ wk,
    const float* __restrict__ wv, const float* __restrict__ wo,
    const float* __restrict__ w1, const float* __restrict__ w2,
    const float* __restrict__ bq, const float* __restrict__ bk,
    const float* __restrict__ bv,
    ushort_t* __restrict__ Wqkv, ushort_t* __restrict__ Wo,
    ushort_t* __restrict__ W1, ushort_t* __restrict__ W2,
    float* __restrict__ bqkv) {
  int i = blockIdx.x * 256 + threadIdx.x;
  if (i < 110592) {                       // Wqkv swizzled, N=576
    int n2 = i / 192, k = i - n2 * 192;
    int part = n2 / 192, n = n2 - part * 192;
    const float* src = part == 0 ? wq : (part == 1 ? wk : wv);
    Wqkv[swz_w(n2, k, 576)] = f2bf(src[k * 192 + n]);
  } else if (i < 147456) {                // Wo swizzled, N=192
    int j = i - 110592;
    int n = j / 192, k = j - n * 192;
    Wo[swz_w(n, k, 192)] = f2bf(wo[k * 192 + n]);
  } else if (i < 294912) {                // W1_t [768][192]
    int j = i - 147456;
    int n = j / 192, k = j - n * 192;
    W1[j] = f2bf(w1[k * 768 + n]);
  } else if (i < 442368) {                // W2_t [192][768]
    int j = i - 294912;
    int n = j / 768, k = j - n * 768;
    W2[j] = f2bf(w2[k * 192 + n]);
  } else if (i < 442944) {                // bqkv [576]
    int j = i - 442368;
    bqkv[j] = j < 192 ? bq[j] : (j < 384 ? bk[j - 192] : bv[j - 384]);
  }
}

// ---------------------------------------------------------------------------
// Fused pre-LN + QKV projection. Block = 32 rows x 576 cols, 256 threads.
// ---------------------------------------------------------------------------
__global__ __launch_bounds__(256) void qkv_ln_kernel(
    const float* __restrict__ xa, const float* __restrict__ xb,
    const int* __restrict__ va, const int* __restrict__ vb,
    const float* __restrict__ g_a, const float* __restrict__ b_a,
    const float* __restrict__ g_b, const float* __restrict__ b_b,
    const ushort_t* __restrict__ Wsw, const float* __restrict__ bias,
    ushort_t* __restrict__ Cb) {
  constexpr int N = 576;
  constexpr int CSB = N + 8;
  __shared__ ushort_t smem[32 * CSB];    // 37.4 KB; As (12.8 KB) overlays
  ushort_t* As = smem;

  int tid = threadIdx.x;
  int w = tid >> 6, lane = tid & 63, l15 = lane & 15, kq = lane >> 4;
  int row0 = blockIdx.x * 32;
  int side = row0 >= ROWS;
  int rb = row0 - side * ROWS;

  // --- phase 1: masked LN, x fp32 -> As bf16 ---
  {
    int row = tid >> 3, l8 = tid & 7;
    const float* xr = (side ? xb : xa) + (size_t)(rb + row) * DD + l8 * 24;
    float v[24];
    float s = 0.f;
#pragma unroll
    for (int j = 0; j < 6; ++j) {
      float4 q = *(const float4*)(xr + j * 4);
      v[j*4+0] = q.x; v[j*4+1] = q.y; v[j*4+2] = q.z; v[j*4+3] = q.w;
      s += q.x + q.y + q.z + q.w;
    }
    s += __shfl_xor(s, 1); s += __shfl_xor(s, 2); s += __shfl_xor(s, 4);
    float mu = s * (1.0f / 192.0f);
    float ss = 0.f;
#pragma unroll
    for (int j = 0; j < 24; ++j) { float d = v[j] - mu; ss += d * d; }
    ss += __shfl_xor(ss, 1); ss += __shfl_xor(ss, 2); ss += __shfl_xor(ss, 4);
    float inv = rsqrtf(ss * (1.0f / 192.0f) + 1e-5f);
    int vld = (side ? vb : va)[rb + row];
    const float* g = side ? g_b : g_a;
    const float* be = side ? b_b : b_a;
    ushort_t ob[24];
#pragma unroll
    for (int j = 0; j < 24; ++j) {
      int col = l8 * 24 + j;
      float r = vld ? (v[j] - mu) * inv * g[col] + be[col] : v[j];
      ob[j] = f2bf(r);
    }
#pragma unroll
    for (int j = 0; j < 3; ++j)
      *(uint4*)(&As[row * 200 + l8 * 24 + j * 8]) = *(const uint4*)(&ob[j * 8]);
  }
  __syncthreads();

  // --- phase 2: GEMM ---
  f32x4 acc[2][9];
#pragma unroll
  for (int qs = 0; qs < 2; ++qs)
#pragma unroll
    for (int nt = 0; nt < 9; ++nt) acc[qs][nt] = (f32x4){0.f, 0.f, 0.f, 0.f};

#pragma unroll 1
  for (int kk = 0; kk < 6; ++kk) {
    bf16x8 af[2];
#pragma unroll
    for (int qs = 0; qs < 2; ++qs)
      af[qs] = *(const bf16x8*)(&As[(qs * 16 + l15) * 200 + kk * 32 + kq * 8]);
    const ushort_t* wp =
        Wsw + ((size_t)(kk * (N >> 4) + w * 9) << 9) + lane * 8;
#pragma unroll
    for (int nt = 0; nt < 9; ++nt) {
      U4BF8 wf;
      wf.u = *(const uint4*)(wp + (nt << 9));
#pragma unroll
      for (int qs = 0; qs < 2; ++qs)
        acc[qs][nt] = __builtin_amdgcn_mfma_f32_16x16x32_bf16(
            af[qs], wf.b, acc[qs][nt], 0, 0, 0);
    }
  }
  __syncthreads();  // As dead; smem reused for C staging

  // --- phase 3: bias -> LDS -> linear full-line bf16 stores ---
  ushort_t* Cs = smem;
#pragma unroll
  for (int nt = 0; nt < 9; ++nt) {
    int col = (w * 9 + nt) * 16 + l15;
    float bb = bias[col];
#pragma unroll
    for (int qs = 0; qs < 2; ++qs)
#pragma unroll
      for (int r = 0; r < 4; ++r)
        Cs[(qs * 16 + kq * 4 + r) * CSB + col] = f2bf(acc[qs][nt][r] + bb);
  }
  __syncthreads();
  constexpr int UPR = (N * 2) / 16;
#pragma unroll
  for (int i = 0; i < (32 * UPR) / 256; ++i) {
    int idx = tid + i * 256;
    int r = idx / UPR, u = idx - r * UPR;
    *(uint4*)(Cb + (size_t)row0 * N + idx * 8) =
        *(const uint4*)(&Cs[r * CSB + u * 8]);
  }
}

// ---------------------------------------------------------------------------
// Fused O-projection + residual + LN-chain. Block = 32 rows x 192 cols.
// Row phase uses INTERLEAVED col ownership (col = j*32 + l8*4) so wave
// stores are full 64B-line contiguous (no write-allocate RMW).
// ---------------------------------------------------------------------------
__global__ __launch_bounds__(256) void oproj_ln_kernel(
    const ushort_t* __restrict__ A, const ushort_t* __restrict__ Wsw,
    const float* __restrict__ bias,
    const float* __restrict__ xa, const float* __restrict__ xb,
    const int* __restrict__ va, const int* __restrict__ vb,
    const float* __restrict__ g_oa, const float* __restrict__ b_oa,
    const float* __restrict__ g_ob, const float* __restrict__ b_ob,
    const float* __restrict__ g_f, const float* __restrict__ b_f,
    float* __restrict__ outf, ushort_t* __restrict__ outb) {
  __shared__ float smemf[32 * 196];      // 25 KB; As (12.8 KB) overlays
  ushort_t* As = (ushort_t*)smemf;

  int tid = threadIdx.x;
  int w = tid >> 6, lane = tid & 63, l15 = lane & 15, kq = lane >> 4;
  int row0 = blockIdx.x * 32;
  int side = row0 >= ROWS;
  int rb = row0 - side * ROWS;

  // stage A (attO) 32x192 bf16
  {
    const ushort_t* ap = A + (size_t)row0 * DD;
#pragma unroll
    for (int i = 0; i < 3; ++i) {
      int idx = tid + i * 256;
      int r = idx / 24, c = (idx - r * 24) * 8;
      *(uint4*)(&As[r * 200 + c]) = *(const uint4*)(ap + idx * 8);
    }
  }
  __syncthreads();

  f32x4 acc[2][3];
#pragma unroll
  for (int qs = 0; qs < 2; ++qs)
#pragma unroll
    for (int nt = 0; nt < 3; ++nt) acc[qs][nt] = (f32x4){0.f, 0.f, 0.f, 0.f};

#pragma unroll 1
  for (int kk = 0; kk < 6; ++kk) {
    bf16x8 af[2];
#pragma unroll
    for (int qs = 0; qs < 2; ++qs)
      af[qs] = *(const bf16x8*)(&As[(qs * 16 + l15) * 200 + kk * 32 + kq * 8]);
    const ushort_t* wp =
        Wsw + ((size_t)(kk * (192 >> 4) + w * 3) << 9) + lane * 8;
#pragma unroll
    for (int nt = 0; nt < 3; ++nt) {
      U4BF8 wf;
      wf.u = *(const uint4*)(wp + (nt << 9));
#pragma unroll
      for (int qs = 0; qs < 2; ++qs)
        acc[qs][nt] = __builtin_amdgcn_mfma_f32_16x16x32_bf16(
            af[qs], wf.b, acc[qs][nt], 0, 0, 0);
    }
  }
  __syncthreads();  // As dead

  // stage C + bias -> Cs fp32
  float* Cs = smemf;
#pragma unroll
  for (int nt = 0; nt < 3; ++nt) {
    int col = (w * 3 + nt) * 16 + l15;
    float bb = bias[col];
#pragma unroll
    for (int qs = 0; qs < 2; ++qs)
#pragma unroll
      for (int r = 0; r < 4; ++r)
        Cs[(qs * 16 + kq * 4 + r) * 196 + col] = acc[qs][nt][r] + bb;
  }
  __syncthreads();

  // row phase: 8 threads/row, interleaved cols (col = j*32 + l8*4)
  int row = tid >> 3, l8 = tid & 7;
  int grow = row0 + row;
  const float* xrow = (side ? xb : xa) + (size_t)(rb + row) * DD;
  const float* crow = &Cs[row * 196];
  float v[24];
  float s = 0.f;
#pragma unroll
  for (int j = 0; j < 6; ++j) {
    int col = j * 32 + l8 * 4;
    float4 q = *(const float4*)(xrow + col);
    v[j*4+0] = crow[col+0] + q.x; v[j*4+1] = crow[col+1] + q.y;
    v[j*4+2] = crow[col+2] + q.z; v[j*4+3] = crow[col+3] + q.w;
    s += v[j*4+0] + v[j*4+1] + v[j*4+2] + v[j*4+3];
  }
  s += __shfl_xor(s, 1); s += __shfl_xor(s, 2); s += __shfl_xor(s, 4);
  float mu = s * (1.0f / 192.0f);
  float ss = 0.f;
#pragma unroll
  for (int j = 0; j < 24; ++j) { float d = v[j] - mu; ss += d * d; }
  ss += __shfl_xor(ss, 1); ss += __shfl_xor(ss, 2); ss += __shfl_xor(ss, 4);
  float inv = rsqrtf(ss * (1.0f / 192.0f) + 1e-5f);
  int vld = (side ? vb : va)[rb + row];
  const float* g1 = side ? g_ob : g_oa;
  const float* b1 = side ? b_ob : b_oa;
  float y[24];
#pragma unroll
  for (int j = 0; j < 6; ++j) {
#pragma unroll
    for (int e = 0; e < 4; ++e) {
      int col = j * 32 + l8 * 4 + e;
      float vv = v[j * 4 + e];
      y[j * 4 + e] = vld ? (vv - mu) * inv * g1[col] + b1[col] : vv;
    }
  }
  float* orow = outf + (size_t)grow * DD;
#pragma unroll
  for (int j = 0; j < 6; ++j) {
    float4 q = {y[j*4+0], y[j*4+1], y[j*4+2], y[j*4+3]};
    *(float4*)(orow + j * 32 + l8 * 4) = q;
  }
  // LN2 -> bf16
  float s2 = 0.f;
#pragma unroll
  for (int j = 0; j < 24; ++j) s2 += y[j];
  s2 += __shfl_xor(s2, 1); s2 += __shfl_xor(s2, 2); s2 += __shfl_xor(s2, 4);
  float mu2 = s2 * (1.0f / 192.0f);
  float ss2 = 0.f;
#pragma unroll
  for (int j = 0; j < 24; ++j) { float e = y[j] - mu2; ss2 += e * e; }
  ss2 += __shfl_xor(ss2, 1); ss2 += __shfl_xor(ss2, 2); ss2 += __shfl_xor(ss2, 4);
  float inv2 = rsqrtf(ss2 * (1.0f / 192.0f) + 1e-5f);
  ushort_t* obrow = outb + (size_t)grow * DD;
#pragma unroll
  for (int j = 0; j < 6; ++j) {
    ushort_t zb[4];
#pragma unroll
    for (int e = 0; e < 4; ++e) {
      int col = j * 32 + l8 * 4 + e;
      float z = vld ? (y[j*4+e] - mu2) * inv2 * g_f[col] + b_f[col] : y[j*4+e];
      zb[e] = f2bf(z);
    }
    *(uint2*)(obrow + j * 32 + l8 * 4) = *(const uint2*)(&zb[0]);
  }
}

// ---------------------------------------------------------------------------
// Fused FFN + final residual + LN, v2 (R9 best): 64 rows, 256 threads,
// 4-wave N-split, 1-deep W1 prefetch only.
// ---------------------------------------------------------------------------
__global__ __launch_bounds__(256, 3) void ffn_fused_kernel(
    const ushort_t* __restrict__ A, const ushort_t* __restrict__ W1t,
    const float* __restrict__ bias1, const ushort_t* __restrict__ W2t,
    const float* __restrict__ bias2,
    const int* __restrict__ va, const int* __restrict__ vb,
    const float* __restrict__ g_f, const float* __restrict__ b_f,
    float* __restrict__ outf) {
  __shared__ float smemf[64 * 196];      // 50.2 KB epilogue Cs; overlays:
  ushort_t* As = (ushort_t*)smemf;       //   As 64*200 us (25.6 KB)
  ushort_t* Hs = As + 64 * 200;          //   Hs 2*64*72 us (18.4 KB)

  int tid = threadIdx.x;
  int w = tid >> 6;
  int lane = tid & 63;
  int l15 = lane & 15;
  int kq = lane >> 4;
  int row0 = blockIdx.x * 64;
  int side = row0 >= ROWS;
  int rb0 = row0 - side * ROWS;

  // stage A: 64 rows x 24 uint4 = 1536 / 256 threads = 6 each
#pragma unroll
  for (int i = 0; i < 6; ++i) {
    int idx = tid + i * 256;
    int r = idx / 24, c = (idx % 24) * 8;
    *(uint4*)(&As[r * 200 + c]) = *(const uint4*)(A + (size_t)(row0 + r) * DD + c);
  }

  const ushort_t* w1p = W1t + (size_t)(w * 16 + l15) * DD + kq * 8;
  const ushort_t* w2p = W2t + (size_t)(w * 48 + l15) * HID + kq * 8;

  U4BF8 w1f[6], w1n[6], w2f[6];
#pragma unroll
  for (int kk = 0; kk < 6; ++kk)
    w1f[kk].u = *(const uint4*)(w1p + kk * 32);  // hc = 0

  f32x4 Cacc[4][3];
#pragma unroll
  for (int qs = 0; qs < 4; ++qs)
#pragma unroll
    for (int nt = 0; nt < 3; ++nt) Cacc[qs][nt] = (f32x4){0.f, 0.f, 0.f, 0.f};

  __syncthreads();   // As ready

  for (int hc = 0; hc < 12; ++hc) {
#pragma unroll
    for (int kk2 = 0; kk2 < 2; ++kk2)
#pragma unroll
      for (int nt = 0; nt < 3; ++nt)
        w2f[kk2 * 3 + nt].u =
            *(const uint4*)(w2p + (size_t)(nt * 16) * HID + hc * 64 + kk2 * 32);

    f32x4 Hacc[4];
#pragma unroll
    for (int qs = 0; qs < 4; ++qs) Hacc[qs] = (f32x4){0.f, 0.f, 0.f, 0.f};
#pragma unroll
    for (int kk = 0; kk < 6; ++kk) {
#pragma unroll
      for (int qs = 0; qs < 4; ++qs) {
        bf16x8 af = *(const bf16x8*)(&As[(qs * 16 + l15) * 200 + kk * 32 + kq * 8]);
        Hacc[qs] = __builtin_amdgcn_mfma_f32_16x16x32_bf16(
            af, w1f[kk].b, Hacc[qs], 0, 0, 0);
      }
    }

    if (hc < 11) {
#pragma unroll
      for (int kk = 0; kk < 6; ++kk)
        w1n[kk].u = *(const uint4*)(w1p + (size_t)(hc + 1) * 64 * DD + kk * 32);
    }

    {
      float bb = bias1[hc * 64 + w * 16 + l15];
      ushort_t* hb = &Hs[(hc & 1) * 4608];
#pragma unroll
      for (int qs = 0; qs < 4; ++qs)
#pragma unroll
        for (int r = 0; r < 4; ++r) {
          float x = Hacc[qs][r] + bb;
          x = 0.5f * x * (1.0f + erff(x * 0.70710678118654752f));
          hb[(qs * 16 + kq * 4 + r) * 72 + w * 16 + l15] = f2bf(x);
        }
    }
    __syncthreads();   // Hs[buf] complete; also fences reads of Hs[buf^1]

#pragma unroll
    for (int kk2 = 0; kk2 < 2; ++kk2) {
      bf16x8 hf[4];
#pragma unroll
      for (int qs = 0; qs < 4; ++qs)
        hf[qs] = *(const bf16x8*)(&Hs[(hc & 1) * 4608 +
                                      (qs * 16 + l15) * 72 + kk2 * 32 + kq * 8]);
#pragma unroll
      for (int nt = 0; nt < 3; ++nt)
#pragma unroll
        for (int qs = 0; qs < 4; ++qs)
          Cacc[qs][nt] = __builtin_amdgcn_mfma_f32_16x16x32_bf16(
              hf[qs], w2f[kk2 * 3 + nt].b, Cacc[qs][nt], 0, 0, 0);
    }

#pragma unroll
    for (int kk = 0; kk < 6; ++kk) w1f[kk] = w1n[kk];
  }
  __syncthreads();   // As/Hs dead; smemf becomes epilogue Cs

  // epilogue: stage C + bias2, then per-row residual + masked LN
  float* Cs = smemf;
#pragma unroll
  for (int qs = 0; qs < 4; ++qs)
#pragma unroll
    for (int nt = 0; nt < 3; ++nt) {
      int col = w * 48 + nt * 16 + l15;
      float bb = bias2[col];
#pragma unroll
      for (int r = 0; r < 4; ++r)
        Cs[(qs * 16 + kq * 4 + r) * 196 + col] = Cacc[qs][nt][r] + bb;
    }
  __syncthreads();

  // 4 threads/row, interleaved cols (col = j*16 + l4*4)
  int row = tid >> 2, l4 = tid & 3;
  int grow = row0 + row;
  float* orow = outf + (size_t)grow * DD;
  const float* crow = &Cs[row * 196];
  float v[48];
  float s = 0.f;
#pragma unroll
  for (int j = 0; j < 12; ++j) {
    int col = j * 16 + l4 * 4;
    float4 q = *(const float4*)(orow + col);   // residual (in-place read)
    v[j*4+0] = crow[col+0] + q.x; v[j*4+1] = crow[col+1] + q.y;
    v[j*4+2] = crow[col+2] + q.z; v[j*4+3] = crow[col+3] + q.w;
    s += v[j*4+0] + v[j*4+1] + v[j*4+2] + v[j*4+3];
  }
  s += __shfl_xor(s, 1); s += __shfl_xor(s, 2);
  float mu = s * (1.0f / 192.0f);
  float ss = 0.f;
#pragma unroll
  for (int j = 0; j < 48; ++j) { float d = v[j] - mu; ss += d * d; }
  ss += __shfl_xor(ss, 1); ss += __shfl_xor(ss, 2);
  float inv = rsqrtf(ss * (1.0f / 192.0f) + 1e-5f);
  int vld = (side ? vb : va)[rb0 + row];
#pragma unroll
  for (int j = 0; j < 12; ++j) {
    int col = j * 16 + l4 * 4;
    float4 q;
#pragma unroll
    for (int e = 0; e < 4; ++e) {
      float vv = v[j * 4 + e];
      ((float*)&q)[e] = vld ? (vv - mu) * inv * g_f[col + e] + b_f[col + e] : vv;
    }
    *(float4*)(orow + col) = q;
  }
}

// ---------------------------------------------------------------------------
// MFMA flash attention (best-measured R3 variant + setprio).
// ---------------------------------------------------------------------------
__global__ __launch_bounds__(256) void attn_mfma_kernel(
    const ushort_t* __restrict__ QKV,
    const int* __restrict__ valid_a, const int* __restrict__ valid_b,
    ushort_t* __restrict__ out) {
  int i = blockIdx.x;
  int gid = ((i >> 5) << 3) | (i & 7);
  int qt = (i >> 3) & 3;
  int side = gid >= BB * HH;
  int grem = side ? gid - BB * HH : gid;
  int h = grem % HH;
  int batch = grem / HH;
  int tid = threadIdx.x;
  int w = tid >> 6;
  int lane = tid & 63;
  int l15 = lane & 15;
  int kq = lane >> 4;

  const int* validq = side ? valid_b : valid_a;
  const int* validk = side ? valid_a : valid_b;
  size_t qrow0  = (size_t)side * ROWS + (size_t)batch * LL;
  size_t kvrow0 = (size_t)(1 - side) * ROWS + (size_t)batch * LL;

  __shared__ ushort_t VsT[2][32 * 72];
  __shared__ ushort_t Ps[4][32 * 72];

  int qbase = qt * 128 + w * 32;

  U4BF8 qfrag[2];
#pragma unroll
  for (int qs = 0; qs < 2; ++qs)
    qfrag[qs].u = *(const uint4*)(QKV + (qrow0 + qbase + qs * 16 + l15) * 576 +
                                  h * DKK + kq * 8);

  // per-(qs,r) fma coefficients: sqf = vq ? SB2 : 0, mq = vq ? 0 : -36
  float sqf[2][4], mq[2][4];
#pragma unroll
  for (int qs = 0; qs < 2; ++qs)
#pragma unroll
    for (int r = 0; r < 4; ++r) {
      int vq = validq[batch * LL + qbase + qs * 16 + kq * 4 + r];
      sqf[qs][r] = vq ? SB2 : 0.0f;
      mq[qs][r]  = vq ? 0.0f : MASKED_X;
    }

  float lsum[2][4];
  f32x4 Oacc[2][2];
#pragma unroll
  for (int qs = 0; qs < 2; ++qs) {
#pragma unroll
    for (int r = 0; r < 4; ++r) lsum[qs][r] = 0.0f;
#pragma unroll
    for (int ds = 0; ds < 2; ++ds) Oacc[qs][ds] = (f32x4){0.f, 0.f, 0.f, 0.f};
  }

  // prologue: load tile-0 V, K, valid
  uint4 vv = *(const uint4*)(QKV + (kvrow0 + lane) * 576 + 384 + h * DKK + w * 8);
  U4BF8 kf[4];
  int vki[4];
#pragma unroll
  for (int ks = 0; ks < 4; ++ks) {
    kf[ks].u = *(const uint4*)(QKV + (kvrow0 + ks * 16 + l15) * 576 +
                               192 + h * DKK + kq * 8);
    vki[ks] = validk[batch * LL + ks * 16 + l15];
  }

  for (int c = 0; c < LL; c += 64) {
    int buf = (c >> 6) & 1;
    // stage this tile's V (regs -> LDS), transposed to [d][k]
    {
      uint_t uu[4] = {vv.x, vv.y, vv.z, vv.w};
#pragma unroll
      for (int j = 0; j < 4; ++j) {
        VsT[buf][(w * 8 + 2 * j) * 72 + lane]     = (ushort_t)(uu[j] & 0xffffu);
        VsT[buf][(w * 8 + 2 * j + 1) * 72 + lane] = (ushort_t)(uu[j] >> 16);
      }
    }
    uint4 vvn;
    if (c + 64 < LL)
      vvn = *(const uint4*)(QKV + (kvrow0 + c + 64 + lane) * 576 +
                            384 + h * DKK + w * 8);
    __syncthreads();   // VsT[buf] ready (prev readers of buf are 2 tiles back)

    // S = Q K^T for this tile (K already in regs)
    f32x4 S[2][4];
    __builtin_amdgcn_s_setprio(1);
#pragma unroll
    for (int ks = 0; ks < 4; ++ks)
#pragma unroll
      for (int qs = 0; qs < 2; ++qs) {
        f32x4 z = (f32x4){0.f, 0.f, 0.f, 0.f};
        S[qs][ks] = __builtin_amdgcn_mfma_f32_16x16x32_bf16(
            qfrag[qs].b, kf[ks].b, z, 0, 0, 0);
      }
    __builtin_amdgcn_s_setprio(0);

    float mkb[4];
#pragma unroll
    for (int ks = 0; ks < 4; ++ks) mkb[ks] = vki[ks] ? 0.0f : MASKED_X;

    // prefetch next tile's K + valid (hidden under softmax+PV)
    U4BF8 kfn[4];
    int vkn[4];
    if (c + 64 < LL) {
#pragma unroll
      for (int ks = 0; ks < 4; ++ks) {
        kfn[ks].u = *(const uint4*)(QKV + (kvrow0 + c + 64 + ks * 16 + l15) * 576 +
                                    192 + h * DKK + kq * 8);
        vkn[ks] = validk[batch * LL + c + 64 + ks * 16 + l15];
      }
    }

    // softmax numerator: p = exp2(fma(S, sqf, min(mq, mkb)))
#pragma unroll
    for (int qs = 0; qs < 2; ++qs)
#pragma unroll
      for (int ks = 0; ks < 4; ++ks)
#pragma unroll
        for (int r = 0; r < 4; ++r) {
          float xs = fmaf(S[qs][ks][r], sqf[qs][r], fminf(mq[qs][r], mkb[ks]));
          float p = __builtin_amdgcn_exp2f(xs);
          lsum[qs][r] += p;
          Ps[w][(qs * 16 + kq * 4 + r) * 72 + ks * 16 + l15] = cvt_bf(p);
        }

    // PV
    __builtin_amdgcn_s_setprio(1);
#pragma unroll
    for (int kh = 0; kh < 2; ++kh) {
      bf16x8 pf[2], vf[2];
#pragma unroll
      for (int qs = 0; qs < 2; ++qs)
        pf[qs] = *(const bf16x8*)(&Ps[w][(qs * 16 + l15) * 72 + kh * 32 + kq * 8]);
#pragma unroll
      for (int ds = 0; ds < 2; ++ds)
        vf[ds] = *(const bf16x8*)(&VsT[buf][(ds * 16 + l15) * 72 + kh * 32 + kq * 8]);
#pragma unroll
      for (int qs = 0; qs < 2; ++qs)
#pragma unroll
        for (int ds = 0; ds < 2; ++ds)
          Oacc[qs][ds] = __builtin_amdgcn_mfma_f32_16x16x32_bf16(
              pf[qs], vf[ds], Oacc[qs][ds], 0, 0, 0);
    }
    __builtin_amdgcn_s_setprio(0);

    vv = vvn;
#pragma unroll
    for (int ks = 0; ks < 4; ++ks) { kf[ks] = kfn[ks]; vki[ks] = vkn[ks]; }
  }

#pragma unroll
  for (int qs = 0; qs < 2; ++qs)
#pragma unroll
    for (int r = 0; r < 4; ++r) {
      float sm = lsum[qs][r];
#pragma unroll
      for (int off = 1; off < 16; off <<= 1) sm += __shfl_xor(sm, off);
      lsum[qs][r] = sm;
    }

#pragma unroll
  for (int qs = 0; qs < 2; ++qs)
#pragma unroll
    for (int ds = 0; ds < 2; ++ds)
#pragma unroll
      for (int r = 0; r < 4; ++r) {
        int q = qbase + qs * 16 + kq * 4 + r;
        out[(qrow0 + q) * DD + h * DKK + ds * 16 + l15] =
            f2bf(Oacc[qs][ds][r] / lsum[qs][r]);
      }
}

// ---------------------------------------------------------------------------
extern "C" void kernel_launch(void* const* d_in, const int* in_sizes, int n_in,
                              void* d_out, int out_size, void* d_ws, size_t ws_size,
                              hipStream_t stream) {
  const float* x_a = (const float*)d_in[0];
  const float* x_b = (const float*)d_in[1];
  const int* valid_a = (const int*)d_in[2];
  const int* valid_b = (const int*)d_in[3];
  const float* ln_a_g = (const float*)d_in[4];
  const float* ln_a_b = (const float*)d_in[5];
  const float* ln_b_g = (const float*)d_in[6];
  const float* ln_b_b = (const float*)d_in[7];
  const float* ln_oa_g = (const float*)d_in[8];
  const float* ln_oa_b = (const float*)d_in[9];
  const float* ln_ob_g = (const float*)d_in[10];
  const float* ln_ob_b = (const float*)d_in[11];
  const float* wq = (const float*)d_in[12];
  const float* bq = (const float*)d_in[13];
  const float* wk = (const float*)d_in[14];
  const float* bk = (const float*)d_in[15];
  const float* wv = (const float*)d_in[16];
  const float* bv = (const float*)d_in[17];
  const float* wo = (const float*)d_in[18];
  const float* bo = (const float*)d_in[19];
  const float* fln_g = (const float*)d_in[20];
  const float* fln_b = (const float*)d_in[21];
  const float* flno_g = (const float*)d_in[22];
  const float* flno_b = (const float*)d_in[23];
  const float* w1 = (const float*)d_in[24];
  const float* b1 = (const float*)d_in[25];
  const float* w2 = (const float*)d_in[26];
  const float* b2 = (const float*)d_in[27];

  // Workspace: weights [0, 887040); lnFull/attO bf16 [2R,192] at 887040;
  // QKV bf16 [2R,576] at 19761408.
  char* wsb = (char*)d_ws;
  ushort_t* Wqkv = (ushort_t*)wsb;
  ushort_t* Wo_t = Wqkv + 110592;
  ushort_t* W1_t = Wo_t + 36864;
  ushort_t* W2_t = W1_t + 147456;
  float*    bqkv = (float*)(W2_t + 147456);
  ushort_t* lnFull = (ushort_t*)(wsb + 887040);
  ushort_t* attO   = lnFull;
  ushort_t* QKV = (ushort_t*)(wsb + 19761408);

  float* out_a = (float*)d_out;   // [2R,192] fp32 contiguous

  dim3 b256(256);
  dim3 gGemm(2 * ROWS / 32);                    // 1536 row-blocks
  dim3 gAttn(BB * HH * 4 * 2);                  // 2304
  dim3 gFFN(2 * ROWS / 64);                     // 768 (64-row ffn blocks)

  hipLaunchKernelGGL(pack_kernel, dim3(1731), b256, 0, stream,
                     wq, wk, wv, wo, w1, w2, bq, bk, bv,
                     Wqkv, Wo_t, W1_t, W2_t, bqkv);

  // 1+2. fused pre-LN + QKV projection, both sides
  hipLaunchKernelGGL(qkv_ln_kernel, gGemm, b256, 0, stream,
                     x_a, x_b, valid_a, valid_b,
                     ln_a_g, ln_a_b, ln_b_g, ln_b_b,
                     Wqkv, bqkv, QKV);

  // 3. attention, both sides (R3 best-measured variant + setprio)
  hipLaunchKernelGGL(attn_mfma_kernel, gAttn, b256, 0, stream,
                     QKV, valid_a, valid_b, attO);

  // 4+5+6. fused O-proj + residual-LN -> d_out, FFN pre-LN -> lnFull bf16
  hipLaunchKernelGGL(oproj_ln_kernel, gGemm, b256, 0, stream,
                     attO, Wo_t, bo, x_a, x_b, valid_a, valid_b,
                     ln_oa_g, ln_oa_b, ln_ob_g, ln_ob_b, fln_g, fln_b,
                     out_a, lnFull);

  // 7+8. fused FFN v2 (64-row, 4-wave) + final residual + LN -> d_out
  hipLaunchKernelGGL(ffn_fused_kernel, gFFN, b256, 0, stream,
                     lnFull, W1_t, b1, W2_t, b2, valid_a, valid_b,
                     flno_g, flno_b, out_a);
}